// Round 10
// baseline (199.198 us; speedup 1.0000x reference)
//
#include <hip/hip_runtime.h>

// BSScanThru: out = brev8( (brev8(a) + brev8(b) + carry-chain) mod 256 ) & ~b
//
// Single-pass, zero inter-block communication, ONE barrier per block.
//
// Carry-lookahead identity: p_j = (c_j == 255) implies g_j = 0 (a wrapped
// byte sum cannot be exactly 255 while also wrapping). Therefore the carry
// into any position equals g of the NEAREST preceding element with c != 255.
// Each block computes its own carry-in by peeking backward from its tile
// base (wave 0: 64 coalesced elems per window, ballot c != 255, take g of
// the highest lane; step back on all-propagate, prob ~2^-512). Indices < 0
// act as {c=0,g=0} -> handles tile 0 / array start with no special case.
// Peek is issued FIRST so its latency overlaps the main tile loads.
//
// Carry propagation via the hardware adder (g,p disjoint => with A=G,
// B=G|P, the carry chain of A+B+cin IS the gp recurrence; carry into bit
// k = P_k ^ S_k since G ^ (G|P) = P):
//   thread level: Cm = P ^ (G + (G|P) + cin)          (32-bit masks)
//   wave level:   bit lane of Pw ^ (Gw + (Gw|Pw) + cw) (64-bit ballots)
//
// Round-10 change: EPT 16 -> 32 (tile 8192). Doubles per-thread loads in
// flight (16 x dwordx4), halves peek+barrier count per byte. Wrapped-sum
// bytes and b-low-bytes packed 4-per-register (saves ~48 VGPRs vs naive
// c[32]/bv[32]). Rationale: round-9 showed occupancy 60->80% bought
// nothing (latency-bound, not wave-starved); actual HBM 3.5 TB/s vs
// fillBuffer's 7.1 -> pipeline depth is the lever left.
//
// No XCD swizzle (round-8: broke natural L3 locality, FETCH +24%, dur
// 150->187). No nontemporal stores (round-7: WRITE +66%, dur 150->260).
//
// Inputs: int32 (values 0..255). Output: int32.

#define BLK 256
#define EPT 32
#define TILE (BLK * EPT)   // 8192

typedef int iv4 __attribute__((ext_vector_type(4)));

// (g,p) packed: bit0 = g, bit1 = p. Identity: g=0,p=1 -> 2u.
__device__ __forceinline__ unsigned gp_combine(unsigned l, unsigned r) {
    unsigned g = (r & 1u) | ((r >> 1) & l & 1u);   // gr | (pr & gl)
    unsigned p = (l >> 1) & (r >> 1) & 1u;         // pl & pr
    return g | (p << 1);
}

__device__ __forceinline__ unsigned brev8(unsigned x) {
    return __brev(x) >> 24;
}

__global__ __launch_bounds__(BLK) void bss_onepass(const int* __restrict__ a,
                                                   const int* __restrict__ b,
                                                   int* __restrict__ out) {
    __shared__ unsigned sh_w[4];
    __shared__ unsigned s_cin;

    const int tid = threadIdx.x;
    const int lane = tid & 63;
    const int wid = tid >> 6;
    const long base0 = (long)blockIdx.x * TILE;
    const int base = (int)base0 + tid * EPT;

    // ---- block carry-in via backward peek (wave 0, issued FIRST) ----
    if (wid == 0) {
        unsigned cb = 0u;
        long w = base0 - 64;
        for (;;) {
            long idx = w + lane;
            unsigned cc = 0u, gg = 0u;   // idx < 0: virtual non-propagating, g=0
            if (idx >= 0) {
                unsigned s = brev8((unsigned)a[idx]) + brev8((unsigned)b[idx]);
                cc = s & 0xFFu;
                gg = s >> 8;
            }
            unsigned long long m = __ballot(cc != 0xFFu);
            if (m) {
                int hi = 63 - __clzll(m);        // nearest to tile base
                cb = (unsigned)__shfl((int)gg, hi, 64);
                break;
            }
            w -= 64;
        }
        if (lane == 0) s_cin = cb;
    }

    // ---- load 32 elems/thread; pack sums + b-bytes, build G/P masks ----
    unsigned cpack[8], bpack[8];
    unsigned G = 0u, P = 0u;
#pragma unroll
    for (int q = 0; q < 8; ++q) {
        iv4 av = *reinterpret_cast<const iv4*>(a + base + q * 4);
        iv4 bv = *reinterpret_cast<const iv4*>(b + base + q * 4);
        unsigned cp = 0u, bp = 0u;
#pragma unroll
        for (int j = 0; j < 4; ++j) {
            unsigned s = brev8((unsigned)av[j]) + brev8((unsigned)bv[j]);
            unsigned cc = s & 0xFFu;
            cp |= cc << (8 * j);
            bp |= ((unsigned)bv[j] & 0xFFu) << (8 * j);
            const int k = q * 4 + j;
            G |= (s >> 8) << k;               // carry generated
            P |= ((cc + 1u) >> 8) << k;       // 1 iff cc==255
        }
        cpack[q] = cp;
        bpack[q] = bp;
    }

    // ---- thread aggregate via adder trick ----
    const unsigned GoP = G | P;
    const unsigned long long S0 = (unsigned long long)G + GoP;
    const unsigned g_t = (unsigned)(S0 >> 32);          // carry-out of 32 elems
    const unsigned p_t = (P == 0xFFFFFFFFu) ? 1u : 0u;

    // ---- wave-level masks (ballot) + wave aggregate ----
    const unsigned long long Gw = __ballot(g_t != 0u);
    const unsigned long long Pw = __ballot(p_t != 0u);
    if (lane == 63) {
        unsigned long long Tw = Gw + (Gw | Pw);
        unsigned g_w = (unsigned)(Tw < Gw);              // 64-bit carry-out
        unsigned p_w = (Pw == ~0ull) ? 1u : 0u;
        sh_w[wid] = g_w | (p_w << 1);
    }
    __syncthreads();   // publishes sh_w AND s_cin

    // carry into this wave: fold earlier-wave aggregates with block carry-in
    unsigned pre = 2u;
#pragma unroll
    for (int w = 0; w < 3; ++w)
        if (w < wid) pre = gp_combine(pre, sh_w[w]);
    const unsigned cb = s_cin;
    const unsigned cw = (pre & 1u) | (((pre >> 1) & 1u) & cb);

    // carry into this thread: bit `lane` of the 64-bit adder carry chain
    const unsigned long long Sw = Gw + (Gw | Pw) + (unsigned long long)cw;
    const unsigned c_t = (unsigned)(((Pw ^ Sw) >> lane) & 1ull);

    // carry into each element: bit k of the 32-bit adder carry chain
    const unsigned Cm = P ^ (unsigned)((unsigned long long)G + GoP + c_t);

    // ---- final byte op, store ----
#pragma unroll
    for (int q = 0; q < 8; ++q) {
        iv4 o;
#pragma unroll
        for (int j = 0; j < 4; ++j) {
            const int k = q * 4 + j;
            unsigned res = (((cpack[q] >> (8 * j)) & 0xFFu) + ((Cm >> k) & 1u)) & 0xFFu;
            o[j] = (int)(brev8(res) & (~(bpack[q] >> (8 * j)) & 0xFFu));
        }
        *reinterpret_cast<iv4*>(out + base + q * 4) = o;
    }
}

extern "C" void kernel_launch(void* const* d_in, const int* in_sizes, int n_in,
                              void* d_out, int out_size, void* d_ws, size_t ws_size,
                              hipStream_t stream) {
    const int* a = (const int*)d_in[0];
    const int* b = (const int*)d_in[1];
    int* out = (int*)d_out;
    const int n = in_sizes[0];      // 67108864
    const int nb = n / TILE;        // 8192

    bss_onepass<<<nb, BLK, 0, stream>>>(a, b, out);
}

// Round 11
// 152.196 us; speedup vs baseline: 1.3088x; 1.3088x over previous
//
#include <hip/hip_runtime.h>

// BSScanThru: out = brev8( (brev8(a) + brev8(b) + carry-chain) mod 256 ) & ~b
//
// Fully wave-decoupled single pass: NO __syncthreads, NO LDS, no
// inter-block or inter-wave communication of any kind.
//
// Carry-lookahead identity: p_j = (c_j == 255) implies g_j = 0 (a wrapped
// byte sum cannot be exactly 255 while also wrapping). Therefore the carry
// into any position equals g of the NEAREST preceding element with c != 255.
// Each WAVE owns a 1024-elem tile and computes its own carry-in by peeking
// backward from its tile base: one 64-elem coalesced window, ballot
// c != 255, take g of the highest such lane; step back on all-propagate
// (prob ~2^-512 per window). Indices < 0 act as {c=0,g=0} -> array start
// and wave 0 need no special case. The peeked window is the previous
// wave-tile's tail -> usually L1-resident (neighbor wave, same CU).
//
// Carry propagation via the hardware adder (g,p disjoint => with A=G,
// B=G|P, the carry chain of A+B+cin IS the gp recurrence; carry into bit
// k = P_k ^ S_k):
//   thread level (16 elems): Cm = P ^ (G + (G|P) + c_t)   (16-bit masks)
//   wave level  (64 thr)  : c_t = bit lane of Pw ^ (Gw + (Gw|Pw) + cb)
//                           with Gw/Pw from two __ballot's.
//
// Geometry: EPT=16 (64 B/lane span — round-10 lesson: EPT=32's 128 B span
// degraded line reuse, FETCH +23%, dur +33%). No XCD swizzle (round-8:
// broke natural L3 locality). No nontemporal stores (round-7: WRITE +66%).
//
// Inputs: int32 (values 0..255). Output: int32.

#define BLK 256
#define EPT 16
#define WTILE (64 * EPT)   // 1024 elems per wave

typedef int iv4 __attribute__((ext_vector_type(4)));

__device__ __forceinline__ unsigned brev8(unsigned x) {
    return __brev(x) >> 24;
}

__global__ __launch_bounds__(BLK) void bss_wave(const int* __restrict__ a,
                                                const int* __restrict__ b,
                                                int* __restrict__ out) {
    const int tid = threadIdx.x;
    const int lane = tid & 63;
    const int wid = tid >> 6;
    const long gw = (long)blockIdx.x * (BLK / 64) + wid;   // global wave id
    const long base0 = gw * WTILE;
    const int base = (int)base0 + lane * EPT;

    // ---- main tile loads issued FIRST (the BW-critical stream) ----
    iv4 av[4], bv[4];
#pragma unroll
    for (int q = 0; q < 4; ++q) {
        av[q] = *reinterpret_cast<const iv4*>(a + base + q * 4);
        bv[q] = *reinterpret_cast<const iv4*>(b + base + q * 4);
    }
    const int* ae = reinterpret_cast<const int*>(av);
    const int* be = reinterpret_cast<const int*>(bv);

    // ---- wave carry-in via backward peek (all 64 lanes) ----
    unsigned cb = 0u;
    {
        long w = base0 - 64;
        for (;;) {
            long idx = w + lane;
            unsigned cc = 0u, gg = 0u;   // idx < 0: virtual non-propagating, g=0
            if (idx >= 0) {
                unsigned s = brev8((unsigned)a[idx]) + brev8((unsigned)b[idx]);
                cc = s & 0xFFu;
                gg = s >> 8;
            }
            unsigned long long m = __ballot(cc != 0xFFu);
            if (m) {
                int hi = 63 - __clzll(m);        // nearest to tile base
                cb = (unsigned)__shfl((int)gg, hi, 64);
                break;
            }
            w -= 64;
        }
    }

    // ---- per-element wrapped sum; G (generate) / P (propagate) masks ----
    unsigned c[EPT];
    unsigned G = 0u, P = 0u;
#pragma unroll
    for (int k = 0; k < EPT; ++k) {
        unsigned s = brev8((unsigned)ae[k]) + brev8((unsigned)be[k]);
        c[k] = s & 0xFFu;
        G |= (s >> 8) << k;               // carry generated
        P |= ((c[k] + 1u) >> 8) << k;     // 1 iff c[k]==255
    }

    // ---- thread aggregate (adder trick, cin=0) ----
    const unsigned GoP = G | P;
    const unsigned g_t = (G + GoP) >> EPT;          // carry-out of 16 elems
    const unsigned p_t = (P == 0xFFFFu) ? 1u : 0u;

    // ---- wave-level carry chain via ballot + 64-bit add ----
    const unsigned long long Gw = __ballot(g_t != 0u);
    const unsigned long long Pw = __ballot(p_t != 0u);
    const unsigned long long Sw = Gw + (Gw | Pw) + (unsigned long long)cb;
    const unsigned c_t = (unsigned)(((Pw ^ Sw) >> lane) & 1ull);

    // ---- per-element carries: bit k of the 16-bit adder carry chain ----
    const unsigned Cm = P ^ (G + GoP + c_t);

    // ---- final byte op, store ----
    iv4 o[4];
    int* of = reinterpret_cast<int*>(o);
#pragma unroll
    for (int k = 0; k < EPT; ++k) {
        unsigned res = (c[k] + ((Cm >> k) & 1u)) & 0xFFu;
        of[k] = (int)(brev8(res) & (~(unsigned)be[k] & 0xFFu));
    }
#pragma unroll
    for (int q = 0; q < 4; ++q)
        *reinterpret_cast<iv4*>(out + base + q * 4) = o[q];
}

extern "C" void kernel_launch(void* const* d_in, const int* in_sizes, int n_in,
                              void* d_out, int out_size, void* d_ws, size_t ws_size,
                              hipStream_t stream) {
    const int* a = (const int*)d_in[0];
    const int* b = (const int*)d_in[1];
    int* out = (int*)d_out;
    const int n = in_sizes[0];          // 67108864
    const int nblk = n / (WTILE * (BLK / 64));   // 16384 blocks (4 waves each)

    bss_wave<<<nblk, BLK, 0, stream>>>(a, b, out);
}